// Round 9
// baseline (1131.567 us; speedup 1.0000x reference)
//
#include <hip/hip_runtime.h>
#include <hip/hip_bf16.h>

#define SEQ 2048
#define BATCH 16
#define HID 512
#define OUT_DIM 10
#define NLAYERS 5
#define M_ROWS (SEQ * BATCH)   // 32768
#define N3H (3 * HID)          // 1536

#define CHUNK 32
#define NSEG (SEQ / CHUNK)     // 64
#define APAD 516               // A row pad: stride 258 dw == 2 mod 32
#define UPAD 1544              // U row pad: stride 772 dw == 4 mod 32

typedef __attribute__((ext_vector_type(8))) _Float16 f16x8;
typedef __attribute__((ext_vector_type(4))) float f32x4;
typedef __attribute__((ext_vector_type(8))) unsigned short u16x8;

__device__ __forceinline__ unsigned short f2h(float x) {
  return __builtin_bit_cast(unsigned short, (_Float16)x);
}
__device__ __forceinline__ float h2f(unsigned short v) {
  return (float)__builtin_bit_cast(_Float16, v);
}
__device__ __forceinline__ float sigm(float x) { return 1.f / (1.f + __expf(-x)); }

// ---------------- f32 -> f16 bulk convert (8 elems/thread) ----------------
__global__ __launch_bounds__(256) void cvt_f32_to_f16(const float* __restrict__ in,
                                                      unsigned short* __restrict__ out) {
  size_t i = ((size_t)blockIdx.x * 256 + threadIdx.x) * 8;
  float4 a = *(const float4*)(in + i);
  float4 b = *(const float4*)(in + i + 4);
  u16x8 r;
  r[0] = f2h(a.x); r[1] = f2h(a.y); r[2] = f2h(a.z); r[3] = f2h(a.w);
  r[4] = f2h(b.x); r[5] = f2h(b.y); r[6] = f2h(b.z); r[7] = f2h(b.w);
  *(u16x8*)(out + i) = r;
}

// ---------------- Fully fused SRU layer: GEMM (U in LDS) + lookback scan ----------------
// Block = (segment s, batch b): computes U[32 l][1536] = A[32][512] x W^T entirely
// in LDS (U never touches HBM), then scans its 512 chains with decoupled lookback.
// 8 waves: each owns 3 n-tiles of 64 cols; B-frags stream straight from W (L2-hot,
// 1.5 MiB/layer) with a 2-deep register prefetch ring; A-frags from LDS. No barriers
// in the K-loop. h updated in place (block reads its own rows at start).
__global__ __launch_bounds__(512, 2) void sru_layer_fused(
    const unsigned short* __restrict__ W,   // [1536][512] f16 (this layer)
    const float* __restrict__ bias,         // [2H] f32
    unsigned long long* __restrict__ FC,    // [NSEG][B][H] packed, pre-zeroed
    unsigned short* hb) {                   // [L][B][H] f16, in/out (in place)
  __shared__ unsigned short Alds[CHUNK][APAD];   // 33.0 KB  (h_in seg = highway x)
  __shared__ unsigned short Ulds[CHUNK][UPAD];   // 98.8 KB  (xt | zf | zr)
  const int tid = threadIdx.x;
  const int s = blockIdx.x >> 4;
  const int b = blockIdx.x & 15;
  const int lane = tid & 63;
  const int wid = tid >> 6;            // 0..7
  const int fr = lane & 15;            // fragment row
  const int ko = (lane >> 4) * 8;      // fragment k offset

  // ---- stage A: 32 rows x 512 k (16 threads/row, 64B each -> coalesced) ----
  {
    const int row = tid >> 4;          // 0..31
    const int k0 = (tid & 15) * 32;
    const unsigned short* src = hb + (((size_t)(s * CHUNK + row) * BATCH + b) << 9) + k0;
#pragma unroll
    for (int j = 0; j < 4; ++j)
      *(u16x8*)&Alds[row][k0 + j * 8] = *(const u16x8*)(src + j * 8);
  }
  __syncthreads();

  // ---- MFMA: 3 n-tiles per wave, K=512 in 16 chunks of 32 ----
#pragma unroll 1
  for (int t = 0; t < 3; ++t) {
    const int n0 = (wid + t * 8) * 64;
    const unsigned short* Wl = W + (size_t)(n0 + fr) * 512 + ko;  // per-lane base

    f32x4 acc[2][4];
#pragma unroll
    for (int mt = 0; mt < 2; ++mt)
#pragma unroll
      for (int nf = 0; nf < 4; ++nf) acc[mt][nf] = (f32x4){0.f, 0.f, 0.f, 0.f};

    f16x8 bring[2][4];
#pragma unroll
    for (int nf = 0; nf < 4; ++nf)
      bring[0][nf] = *(const f16x8*)(Wl + nf * 16 * 512);

#pragma unroll
    for (int kc = 0; kc < 16; ++kc) {
      if (kc + 1 < 16) {
#pragma unroll
        for (int nf = 0; nf < 4; ++nf)
          bring[(kc + 1) & 1][nf] = *(const f16x8*)(Wl + nf * 16 * 512 + (kc + 1) * 32);
      }
      f16x8 af0 = *(const f16x8*)&Alds[fr][kc * 32 + ko];
      f16x8 af1 = *(const f16x8*)&Alds[16 + fr][kc * 32 + ko];
#pragma unroll
      for (int nf = 0; nf < 4; ++nf) {
        acc[0][nf] = __builtin_amdgcn_mfma_f32_16x16x32_f16(af0, bring[kc & 1][nf], acc[0][nf], 0, 0, 0);
        acc[1][nf] = __builtin_amdgcn_mfma_f32_16x16x32_f16(af1, bring[kc & 1][nf], acc[1][nf], 0, 0, 0);
      }
    }

    // epilogue: acc -> U_lds (C/D map: col = lane&15, row = (lane>>4)*4 + j)
    const int er = (lane >> 4) * 4;
#pragma unroll
    for (int mt = 0; mt < 2; ++mt)
#pragma unroll
      for (int nf = 0; nf < 4; ++nf) {
        const int row = mt * 16 + er;
        const int col = n0 + nf * 16 + fr;
#pragma unroll
        for (int j = 0; j < 4; ++j) Ulds[row + j][col] = f2h(acc[mt][nf][j]);
      }
  }
  __syncthreads();   // U tile complete

  // ---- scan: one chain per thread (h = tid) ----
  const int h = tid;
  const float bf = bias[h], br = bias[HID + h];

  // phase 1: local (F, C | c0 = 0) from LDS
  float F = 1.f, c = 0.f;
#pragma unroll
  for (int i = 0; i < CHUNK; ++i) {
    float xt = h2f(Ulds[i][h]);
    float zf = h2f(Ulds[i][HID + h]);
    float f = sigm(zf + bf);
    c = f * c + (1.f - f) * xt;
    F *= f;
  }

  // publish: one 64-bit word; F negated so sign bit tags "published"
  const size_t ch = ((size_t)s * BATCH + b) * HID + h;
  atomicExch(&FC[ch],
             ((unsigned long long)__builtin_bit_cast(unsigned, c) << 32) |
                 __builtin_bit_cast(unsigned, -F));

  // lookback: c_in = sum_{j<s} C_j * prod_{j<k<s} F_k  (early exit on underflow)
  float ci = 0.f, P = 1.f;
  for (int j = s - 1; j >= 0; --j) {
    unsigned long long v;
    do { v = atomicAdd(&FC[((size_t)j * BATCH + b) * HID + h], 0ULL); }
    while (!(v & 0x80000000ULL));
    float Fj = -__builtin_bit_cast(float, (unsigned)v);
    float Cj = __builtin_bit_cast(float, (unsigned)(v >> 32));
    ci += P * Cj;
    P *= Fj;
    if (P == 0.f) break;
  }

  // phase 3: replay with carry; highway x from Alds; h written in place
  float cc = ci;
  unsigned short* hp = hb + (((size_t)(s * CHUNK) * BATCH + b) << 9) + h;
#pragma unroll
  for (int i = 0; i < CHUNK; ++i) {
    float xt = h2f(Ulds[i][h]);
    float zf = h2f(Ulds[i][HID + h]);
    float zr = h2f(Ulds[i][2 * HID + h]);
    float f = sigm(zf + bf);
    float r = sigm(zr + br);
    cc = f * cc + (1.f - f) * xt;
    float xv = h2f(Alds[i][h]);
    hp[(size_t)i * BATCH * HID] = f2h(r * cc + (1.f - r) * xv);
  }
}

// ---------------- FC head (f16 H, f32 math) ----------------
#define FCR 16
__global__ __launch_bounds__(256) void fc_kernel(const unsigned short* __restrict__ H,
                                                 const float* __restrict__ W,
                                                 const float* __restrict__ bv,
                                                 float* __restrict__ out) {
  __shared__ float hs[FCR][516];
  __shared__ float ws[OUT_DIM][516];
  const int tid = threadIdx.x;
  const size_t m0 = (size_t)blockIdx.x * FCR;
#pragma unroll
  for (int i = 0; i < 4; ++i) {
    int f = tid + i * 256;
    int row = f >> 6;     // 0..15
    int kq = f & 63;      // 8-elem group
    u16x8 v = *(const u16x8*)(H + (m0 + row) * 512 + kq * 8);
#pragma unroll
    for (int j = 0; j < 8; ++j) hs[row][kq * 8 + j] = h2f(v[j]);
  }
#pragma unroll
  for (int i = 0; i < 5; ++i) {
    int f = tid + i * 256;
    int row = f >> 7;     // 0..9
    int kq = f & 127;
    float4 v = *(const float4*)(W + row * 512 + kq * 4);
    *(float4*)&ws[row][kq * 4] = v;
  }
  __syncthreads();
  if (tid < FCR * OUT_DIM) {
    int row = tid / OUT_DIM;
    int o = tid - row * OUT_DIM;
    float acc = bv[o];
#pragma unroll 8
    for (int k = 0; k < 512; ++k) acc += hs[row][k] * ws[o][k];
    out[(m0 + row) * OUT_DIM + o] = acc;
  }
}

extern "C" void kernel_launch(void* const* d_in, const int* in_sizes, int n_in,
                              void* d_out, int out_size, void* d_ws, size_t ws_size,
                              hipStream_t stream) {
  const float* x   = (const float*)d_in[0];  // [2048][16][512]
  const float* Ws  = (const float*)d_in[1];  // [5][1536][512]
  const float* bs  = (const float*)d_in[2];  // [5][1024]
  const float* fcW = (const float*)d_in[3];  // [10][512]
  const float* fcb = (const float*)d_in[4];  // [10]
  float* out = (float*)d_out;

  char* ws = (char*)d_ws;
  const size_t MiB = 1024 * 1024;
  unsigned short* hb = (unsigned short*)ws;                       // 32 MiB [M][512] f16
  unsigned short* Wh = (unsigned short*)(ws + 32 * MiB);          // 7.5 MiB f16 weights
  unsigned long long* FC = (unsigned long long*)(ws + 40 * MiB);  // 4 MiB lookback
  // total 44 MiB <= 256 MiB workspace

  // one-time converts (per call; inputs never mutated)
  cvt_f32_to_f16<<<(NLAYERS * N3H * HID) / (256 * 8), 256, 0, stream>>>(Ws, Wh);
  cvt_f32_to_f16<<<(M_ROWS * HID) / (256 * 8), 256, 0, stream>>>(x, hb);

  for (int l = 0; l < NLAYERS; ++l) {
    hipMemsetAsync(FC, 0, (size_t)NSEG * BATCH * HID * 8, stream);
    sru_layer_fused<<<NSEG * BATCH, 512, 0, stream>>>(
        Wh + (size_t)l * N3H * HID, bs + (size_t)l * 2 * HID, FC, hb);
  }
  fc_kernel<<<M_ROWS / FCR, 256, 0, stream>>>(hb, fcW, fcb, out);
}

// Round 10
// 628.725 us; speedup vs baseline: 1.7998x; 1.7998x over previous
//
#include <hip/hip_runtime.h>
#include <hip/hip_bf16.h>

#define SEQ 2048
#define BATCH 16
#define HID 512
#define OUT_DIM 10
#define NLAYERS 5
#define M_ROWS (SEQ * BATCH)   // 32768
#define N3H (3 * HID)          // 1536
#define GK HID                 // GEMM K

#define CHUNK 32
#define NSEG (SEQ / CHUNK)     // 64

typedef __attribute__((ext_vector_type(8))) _Float16 f16x8;
typedef __attribute__((ext_vector_type(4))) float f32x4;
typedef __attribute__((ext_vector_type(8))) unsigned short u16x8;

__device__ __forceinline__ unsigned short f2h(float x) {
  return __builtin_bit_cast(unsigned short, (_Float16)x);
}
__device__ __forceinline__ float h2f(unsigned short v) {
  return (float)__builtin_bit_cast(_Float16, v);
}
__device__ __forceinline__ float sigm(float x) { return 1.f / (1.f + __expf(-x)); }

// ---------------- f32 -> f16 bulk convert (8 elems/thread) ----------------
__global__ __launch_bounds__(256) void cvt_f32_to_f16(const float* __restrict__ in,
                                                      unsigned short* __restrict__ out) {
  size_t i = ((size_t)blockIdx.x * 256 + threadIdx.x) * 8;
  float4 a = *(const float4*)(in + i);
  float4 b = *(const float4*)(in + i + 4);
  u16x8 r;
  r[0] = f2h(a.x); r[1] = f2h(a.y); r[2] = f2h(a.z); r[3] = f2h(a.w);
  r[4] = f2h(b.x); r[5] = f2h(b.y); r[6] = f2h(b.z); r[7] = f2h(b.w);
  *(u16x8*)(out + i) = r;
}

// ---------------- f16 MFMA GEMM: 3-buffer ring, counted vmcnt(4) ----------------
// C[m][n] = sum_k A[m][k] * B[n][k]. A:[M][512], B:[1536][512] (B^T), C:[M][1536] f16.
// 128x128 tile, 256 thr (4 waves, 64x64 quadrants). Instead of __syncthreads()
// per K-step (drains vmcnt(0) -> the 2-phase structural stall), keep a 3-deep
// LDS buffer ring with s_waitcnt vmcnt(4): the NEXT tile's 4 loads stay in
// flight across the barrier. Buffer overwritten at iter kt was last read at
// kt-1; all waves' kt-1 ds_reads are MFMA-consumed before they reach barrier kt.
__global__ __launch_bounds__(256) void gemm_mfma(const unsigned short* __restrict__ A,
                                                 const unsigned short* __restrict__ B,
                                                 unsigned short* __restrict__ C) {
  // 3 staging buffers (A tile @ +0, B tile @ +4096); C-transpose (128x136
  // = 17408 f16) reuses the union at epilogue.
  __shared__ unsigned short lds[3][8192];
  const int tid = threadIdx.x;
  const int nwg = (M_ROWS / 128) * (N3H / 128);      // 3072
  const int cpx = nwg / 8;                           // 384 (bijective: 3072 % 8 == 0)
  const int swz = (blockIdx.x % 8) * cpx + blockIdx.x / 8;
  const int bm = swz / (N3H / 128);
  const int bn = swz % (N3H / 128);
  const int lane = tid & 63;
  const int wid = tid >> 6;
  const int wm = (wid >> 1) * 64, wn = (wid & 1) * 64;

  const unsigned short* Ag = A + (size_t)bm * 128 * GK;
  const unsigned short* Bg = B + (size_t)bn * 128 * GK;

  const int s0 = tid, s1 = tid + 256;
  const int r0 = s0 >> 2, c0 = (s0 & 3) * 8;
  const int r1 = s1 >> 2, c1 = (s1 & 3) * 8;

  const int fr = lane & 15;         // fragment row (M for A, N for B)
  const int ko = (lane >> 4) * 8;   // fragment k offset (8 contiguous)

  f32x4 acc[4][4];
#pragma unroll
  for (int i = 0; i < 4; ++i)
#pragma unroll
    for (int j = 0; j < 4; ++j) acc[i][j] = (f32x4){0.f, 0.f, 0.f, 0.f};

#define STAGE(buf, k0)                                                                              \
  {                                                                                                 \
    __builtin_amdgcn_global_load_lds(                                                               \
        (const __attribute__((address_space(1))) void*)(Ag + (size_t)r0 * GK + (k0) + c0),          \
        (__attribute__((address_space(3))) void*)&lds[buf][s0 * 8], 16, 0, 0);                      \
    __builtin_amdgcn_global_load_lds(                                                               \
        (const __attribute__((address_space(1))) void*)(Ag + (size_t)r1 * GK + (k0) + c1),          \
        (__attribute__((address_space(3))) void*)&lds[buf][s1 * 8], 16, 0, 0);                      \
    __builtin_amdgcn_global_load_lds(                                                               \
        (const __attribute__((address_space(1))) void*)(Bg + (size_t)r0 * GK + (k0) + c0),          \
        (__attribute__((address_space(3))) void*)&lds[buf][4096 + s0 * 8], 16, 0, 0);               \
    __builtin_amdgcn_global_load_lds(                                                               \
        (const __attribute__((address_space(1))) void*)(Bg + (size_t)r1 * GK + (k0) + c1),          \
        (__attribute__((address_space(3))) void*)&lds[buf][4096 + s1 * 8], 16, 0, 0);               \
  }

  STAGE(0, 0);
  STAGE(1, 32);
#pragma unroll 1
  for (int kt = 0; kt < 16; ++kt) {
    // wait for buf[kt%3]'s 4 loads only; the next tile's 4 stay in flight
    if (kt < 15) {
      asm volatile("s_waitcnt vmcnt(4)" ::: "memory");
    } else {
      asm volatile("s_waitcnt vmcnt(0)" ::: "memory");
    }
    __builtin_amdgcn_s_barrier();
    __builtin_amdgcn_sched_barrier(0);   // pin: nothing moves above the barrier
    if (kt + 2 < 16) STAGE((kt + 2) % 3, (kt + 2) * 32);
    const int cb = kt % 3;
    f16x8 af[4], bfr[4];
#pragma unroll
    for (int t = 0; t < 4; ++t) {
      af[t]  = *(const f16x8*)&lds[cb][(wm + t * 16 + fr) * 32 + ko];
      bfr[t] = *(const f16x8*)&lds[cb][4096 + (wn + t * 16 + fr) * 32 + ko];
    }
#pragma unroll
    for (int mt = 0; mt < 4; ++mt)
#pragma unroll
      for (int nt = 0; nt < 4; ++nt)
        acc[mt][nt] = __builtin_amdgcn_mfma_f32_16x16x32_f16(af[mt], bfr[nt], acc[mt][nt], 0, 0, 0);
  }
#undef STAGE

  // ---- coalesced C-write via LDS transpose (row stride padded to 136) ----
  __syncthreads();  // all waves done reading buffers
  unsigned short* cl = &lds[0][0];
  const int er = (lane >> 4) * 4;   // C/D layout: col=lane&15, row=(lane>>4)*4+reg
#pragma unroll
  for (int mt = 0; mt < 4; ++mt)
#pragma unroll
    for (int nt = 0; nt < 4; ++nt) {
      const int row = wm + mt * 16 + er;
      const int col = wn + nt * 16 + fr;
#pragma unroll
      for (int j = 0; j < 4; ++j) cl[(row + j) * 136 + col] = f2h(acc[mt][nt][j]);
    }
  __syncthreads();
  unsigned short* Cb = C + (size_t)bm * 128 * N3H + bn * 128;
#pragma unroll
  for (int i = 0; i < 8; ++i) {
    int flat = i * 2048 + tid * 8;
    int r = flat >> 7, c = flat & 127;
    *(u16x8*)(Cb + (size_t)r * N3H + c) = *(const u16x8*)&cl[r * 136 + c];
  }
}

// ---------------- Fused single-pass SRU scan (decoupled lookback) ----------------
// Grid: 64 segments x 16 batch = 1024 blocks; 256 thr x 2h = 512 chains/block.
// Protocol: per (segment, chain) publish (F, C) packed in ONE 64-bit word via
// atomicExch; F stored NEGATED so the low word's sign bit doubles as the
// "published" tag. FC epoch buffer is pre-zeroed (one memset for all layers).
__global__ __launch_bounds__(256, 4) void sru_scan_fused(
    const unsigned short* __restrict__ U,     // [L][B][3H] f16: xt | zf | zr
    const float* __restrict__ bias,           // [2H]
    unsigned long long* __restrict__ FC,      // [NSEG][B][H] packed, pre-zeroed
    unsigned short* hb) {                     // [L][B][H] f16, updated in place
  const int s = blockIdx.x >> 4;
  const int b = blockIdx.x & 15;
  const int h0 = threadIdx.x << 1;
  const float bf0 = bias[h0], bf1 = bias[h0 + 1];
  const float br0 = bias[HID + h0], br1 = bias[HID + h0 + 1];

  const size_t rowstep = (size_t)BATCH * N3H;
  const unsigned short* Up = U + ((size_t)(s * CHUNK) * BATCH + b) * N3H + h0;

  // ---- phase 1: local (F, C | c0=0); retain packed (f16 f, f16 xt) per step
  unsigned fx0[CHUNK], fx1[CHUNK];
  float F0 = 1.f, F1 = 1.f, c0 = 0.f, c1 = 0.f;
#pragma unroll
  for (int i = 0; i < CHUNK; ++i) {
    const unsigned short* p = Up + (size_t)i * rowstep;
    unsigned xt = *(const unsigned*)(p);
    unsigned zf = *(const unsigned*)(p + HID);
    unsigned short fh0 = f2h(sigm(h2f((unsigned short)zf) + bf0));
    unsigned short fh1 = f2h(sigm(h2f((unsigned short)(zf >> 16)) + bf1));
    float f0 = h2f(fh0), f1 = h2f(fh1);
    c0 = f0 * c0 + (1.f - f0) * h2f((unsigned short)xt);
    c1 = f1 * c1 + (1.f - f1) * h2f((unsigned short)(xt >> 16));
    F0 *= f0; F1 *= f1;
    fx0[i] = (xt & 0xffffu) | ((unsigned)fh0 << 16);
    fx1[i] = (xt >> 16) | ((unsigned)fh1 << 16);
  }

  // ---- publish (single-word atomic; no fence needed)
  const size_t ch = ((size_t)s * BATCH + b) * HID + h0;
  atomicExch(&FC[ch],
             ((unsigned long long)__builtin_bit_cast(unsigned, c0) << 32) |
                 __builtin_bit_cast(unsigned, -F0));
  atomicExch(&FC[ch + 1],
             ((unsigned long long)__builtin_bit_cast(unsigned, c1) << 32) |
                 __builtin_bit_cast(unsigned, -F1));

  // ---- lookback: c_in = sum_{j<s} C_j * prod_{j<k<s} F_k
  float ci0 = 0.f, ci1 = 0.f, P0 = 1.f, P1 = 1.f;
  for (int j = s - 1; j >= 0; --j) {
    const size_t cj = ((size_t)j * BATCH + b) * HID + h0;
    unsigned long long v0, v1;
    do { v0 = atomicAdd(&FC[cj], 0ULL); } while (!(v0 & 0x80000000ULL));
    do { v1 = atomicAdd(&FC[cj + 1], 0ULL); } while (!(v1 & 0x80000000ULL));
    float Fj0 = -__builtin_bit_cast(float, (unsigned)v0);
    float Cj0 = __builtin_bit_cast(float, (unsigned)(v0 >> 32));
    float Fj1 = -__builtin_bit_cast(float, (unsigned)v1);
    float Cj1 = __builtin_bit_cast(float, (unsigned)(v1 >> 32));
    ci0 += P0 * Cj0; P0 *= Fj0;
    ci1 += P1 * Cj1; P1 *= Fj1;
    if (P0 == 0.f && P1 == 0.f) break;   // product underflow: rest contributes 0
  }

  // ---- phase 3: replay with carry; read zr + x, write h in place
  float cc0 = ci0, cc1 = ci1;
  const size_t hstep = (size_t)BATCH * HID;
  unsigned short* hp = hb + ((size_t)(s * CHUNK) * BATCH + b) * HID + h0;
#pragma unroll
  for (int i = 0; i < CHUNK; ++i) {
    unsigned zr = *(const unsigned*)(Up + (size_t)i * rowstep + 2 * HID);
    unsigned xv = *(const unsigned*)(hp + (size_t)i * hstep);
    float f0 = h2f((unsigned short)(fx0[i] >> 16));
    float f1 = h2f((unsigned short)(fx1[i] >> 16));
    cc0 = f0 * cc0 + (1.f - f0) * h2f((unsigned short)fx0[i]);
    cc1 = f1 * cc1 + (1.f - f1) * h2f((unsigned short)fx1[i]);
    float r0 = sigm(h2f((unsigned short)zr) + br0);
    float r1 = sigm(h2f((unsigned short)(zr >> 16)) + br1);
    float hn0 = r0 * cc0 + (1.f - r0) * h2f((unsigned short)xv);
    float hn1 = r1 * cc1 + (1.f - r1) * h2f((unsigned short)(xv >> 16));
    *(unsigned*)(hp + (size_t)i * hstep) = (unsigned)f2h(hn0) | ((unsigned)f2h(hn1) << 16);
  }
}

// ---------------- FC head (f16 H, f32 math) ----------------
#define FCR 16
__global__ __launch_bounds__(256) void fc_kernel(const unsigned short* __restrict__ H,
                                                 const float* __restrict__ W,
                                                 const float* __restrict__ bv,
                                                 float* __restrict__ out) {
  __shared__ float hs[FCR][516];
  __shared__ float ws[OUT_DIM][516];
  const int tid = threadIdx.x;
  const size_t m0 = (size_t)blockIdx.x * FCR;
#pragma unroll
  for (int i = 0; i < 4; ++i) {
    int f = tid + i * 256;
    int row = f >> 6;     // 0..15
    int kq = f & 63;      // 8-elem group
    u16x8 v = *(const u16x8*)(H + (m0 + row) * 512 + kq * 8);
#pragma unroll
    for (int j = 0; j < 8; ++j) hs[row][kq * 8 + j] = h2f(v[j]);
  }
#pragma unroll
  for (int i = 0; i < 5; ++i) {
    int f = tid + i * 256;
    int row = f >> 7;     // 0..9
    int kq = f & 127;
    float4 v = *(const float4*)(W + row * 512 + kq * 4);
    *(float4*)&ws[row][kq * 4] = v;
  }
  __syncthreads();
  if (tid < FCR * OUT_DIM) {
    int row = tid / OUT_DIM;
    int o = tid - row * OUT_DIM;
    float acc = bv[o];
#pragma unroll 8
    for (int k = 0; k < 512; ++k) acc += hs[row][k] * ws[o][k];
    out[(m0 + row) * OUT_DIM + o] = acc;
  }
}

extern "C" void kernel_launch(void* const* d_in, const int* in_sizes, int n_in,
                              void* d_out, int out_size, void* d_ws, size_t ws_size,
                              hipStream_t stream) {
  const float* x   = (const float*)d_in[0];  // [2048][16][512]
  const float* Ws  = (const float*)d_in[1];  // [5][1536][512]
  const float* bs  = (const float*)d_in[2];  // [5][1024]
  const float* fcW = (const float*)d_in[3];  // [10][512]
  const float* fcb = (const float*)d_in[4];  // [10]
  float* out = (float*)d_out;

  char* ws = (char*)d_ws;
  const size_t MiB = 1024 * 1024;
  unsigned short* Ub = (unsigned short*)ws;                  // 96 MiB: [M][1536] f16
  unsigned short* hb = (unsigned short*)(ws + 96 * MiB);     // 32 MiB: [M][512] f16
  unsigned short* Wh = (unsigned short*)(ws + 128 * MiB);    // 7.5 MiB f16 weights
  unsigned long long* FC = (unsigned long long*)(ws + 136 * MiB);  // 20 MiB: 5 epochs
  // total 156 MiB <= 256 MiB workspace

  // one-time converts + single lookback-buffer clear for ALL layers
  hipMemsetAsync(FC, 0, (size_t)NLAYERS * NSEG * BATCH * HID * 8, stream);
  cvt_f32_to_f16<<<(NLAYERS * N3H * HID) / (256 * 8), 256, 0, stream>>>(Ws, Wh);
  cvt_f32_to_f16<<<(M_ROWS * HID) / (256 * 8), 256, 0, stream>>>(x, hb);

  for (int l = 0; l < NLAYERS; ++l) {
    gemm_mfma<<<(M_ROWS / 128) * (N3H / 128), 256, 0, stream>>>(
        hb, Wh + (size_t)l * N3H * HID, Ub);
    sru_scan_fused<<<NSEG * BATCH, 256, 0, stream>>>(
        Ub, bs + (size_t)l * 2 * HID,
        FC + (size_t)l * NSEG * BATCH * HID, hb);
  }
  fc_kernel<<<M_ROWS / FCR, 256, 0, stream>>>(hb, fcW, fcb, out);
}